// Round 19
// baseline (290.046 us; speedup 1.0000x reference)
//
#include <hip/hip_runtime.h>
#include <hip/hip_bf16.h>

static constexpr int C  = 21;
static constexpr int H  = 384;
static constexpr int W  = 384;
static constexpr int HW = H * W;
static constexpr float NCLIQ = 5.0f;

typedef unsigned short u16;
typedef unsigned int   u32;

// function-local constexpr taps: exp(-o^2/18), o=-6..6 — folds to immediates
#define GKDEF constexpr float gk[13] = { \
    0.13533528f, 0.24935222f, 0.41111229f, 0.60653066f, 0.80073740f, \
    0.94595947f, 1.00000000f, 0.94595947f, 0.80073740f, 0.60653066f, \
    0.41111229f, 0.24935222f, 0.13533528f }

__device__ __forceinline__ float bfu2f(u16 u) {
    return __uint_as_float(((u32)u) << 16);
}
// packed pair -> two floats (lo/hi bf16 halves of a u32)
__device__ __forceinline__ float bflo(u32 v) { return __uint_as_float(v << 16); }
__device__ __forceinline__ float bfhi(u32 v) { return __uint_as_float(v & 0xFFFF0000u); }
__device__ __forceinline__ u16 f2bfu(float f) {
    unsigned x = __float_as_uint(f);
    return (u16)((x + 0x7FFF + ((x >> 16) & 1)) >> 16);   // RNE; inputs finite
}

// ---- prep: q/un planar + wtab + norms + msum + M1/M2 + fused ST(iter 0) ----
__global__ __launch_bounds__(256)
void k_prep(const float* __restrict__ un, const float* __restrict__ rgb,
            const int* __restrict__ sp,
            const float* __restrict__ Wsp, const float* __restrict__ Wbi,
            const float* __restrict__ Cm,
            float* __restrict__ q, float* __restrict__ unp,
            u16* __restrict__ wtab, float* __restrict__ msum,
            float* __restrict__ inv_sp, float* __restrict__ inv_bn,
            float* __restrict__ M1, float* __restrict__ M2,
            u16* __restrict__ t1, u16* __restrict__ t2) {
    GKDEF;
    __shared__ float sM1[C * C], sM2[C * C];
    for (int i = threadIdx.x; i < C * C; i += 256) {
        int c = i / C, k = i - c * C;
        float a1 = 0.f, a2 = 0.f;
        for (int j = 0; j < C; j++) {
            float cm = Cm[c * C + j];
            a1 += cm * Wsp[j * C + k];
            a2 += cm * Wbi[j * C + k];
        }
        sM1[i] = a1;
        sM2[i] = a2;
        if (blockIdx.x == 0) { M1[i] = a1; M2[i] = a2; }
    }

    int bid = blockIdx.x;                       // 576, XCD-swizzled
    int chunk = (bid & 7) * 72 + (bid >> 3);
    int p = chunk * 256 + threadIdx.x;
    int y = p / W, x = p - y * W;

    float v[C];
    for (int c = 0; c < C; c++) {
        v[c] = un[p * C + c];
        q[c * HW + p] = v[c];
        unp[c * HW + p] = v[c];
    }

    float r0 = rgb[p * 3 + 0];
    float g0 = rgb[p * 3 + 1];
    float b0 = rgb[p * 3 + 2];
    float s = 0.f;
    int t = 0;
    for (int dy = -2; dy <= 2; dy++) {
        for (int dx = -2; dx <= 2; dx++, t++) {
            int sy = y - dy, sx = x - dx;
            float wv = 0.f;
            if (sy >= 0 && sy < H && sx >= 0 && sx < W) {
                int o = sy * W + sx;
                float dr = r0 - rgb[o * 3 + 0];
                float dg = g0 - rgb[o * 3 + 1];
                float db = b0 - rgb[o * 3 + 2];
                wv = expf(-(float)(dy * dy + dx * dx) * (1.0f / 51200.0f)) *
                     expf(-(dr * dr + dg * dg + db * db) * (1.0f / 18.0f));
            }
            u16 wu = f2bfu(wv);
            wtab[(size_t)t * HW + p] = wu;
            s += bfu2f(wu);
        }
    }
    inv_bn[p] = 1.0f / s;

    float fy = 0.f, fx = 0.f;
    for (int o = -6; o <= 6; o++) {
        if (y - o >= 0 && y - o < H) fy += gk[o + 6];
        if (x - o >= 0 && x - o < W) fx += gk[o + 6];
    }
    inv_sp[p] = 1.0f / (fy * fx);

    int vv = sp[x * W + y];   // sp_map transposed: sp[x][y]
    msum[p] = (vv == 5 || vv == 37 || vv == 81 || vv == 150 || vv == 230) ? 1.0f : 0.0f;

    // ---- fused ST for iteration 0 ----
    __syncthreads();
    float mx = -1e30f;
#pragma unroll
    for (int c = 0; c < C; c++) mx = fmaxf(mx, v[c]);
    float ssum = 0.f;
#pragma unroll
    for (int c = 0; c < C; c++) {
        v[c] = expf(v[c] - mx);
        ssum += v[c];
    }
    float inv = 1.0f / ssum;
    float a1[C], a2[C];
#pragma unroll
    for (int c = 0; c < C; c++) { a1[c] = 0.f; a2[c] = 0.f; }
#pragma unroll
    for (int k = 0; k < C; k++) {
        float e = v[k];
#pragma unroll
        for (int c = 0; c < C; c++) {
            a1[c] += sM1[c * C + k] * e;
            a2[c] += sM2[c * C + k] * e;
        }
    }
#pragma unroll
    for (int c = 0; c < C; c++) {
        t1[c * HW + p] = f2bfu(a1[c] * inv);
        t2[c * HW + p] = f2bfu(a2[c] * inv);
    }
}

// fused softmax + both 21x21 matmuls (iters 1..4). M via uniform s_loads.
__global__ __launch_bounds__(256)
void k_ST(const float* __restrict__ q, const float* __restrict__ M1,
          const float* __restrict__ M2,
          u16* __restrict__ t1, u16* __restrict__ t2) {
    int bid = blockIdx.x;                  // 576, XCD-swizzled
    int chunk = (bid & 7) * 72 + (bid >> 3);
    int p = chunk * 256 + threadIdx.x;
    float v[C];
    float mx = -1e30f;
#pragma unroll
    for (int c = 0; c < C; c++) {
        v[c] = q[c * HW + p];
        mx = fmaxf(mx, v[c]);
    }
    float s = 0.f;
#pragma unroll
    for (int c = 0; c < C; c++) {
        v[c] = expf(v[c] - mx);
        s += v[c];
    }
    float inv = 1.0f / s;
    float a1[C], a2[C];
#pragma unroll
    for (int c = 0; c < C; c++) { a1[c] = 0.f; a2[c] = 0.f; }
#pragma unroll
    for (int k = 0; k < C; k++) {
        float e = v[k];
#pragma unroll
        for (int c = 0; c < C; c++) {
            a1[c] += M1[c * C + k] * e;   // uniform index -> s_load
            a2[c] += M2[c * C + k] * e;
        }
    }
#pragma unroll
    for (int c = 0; c < C; c++) {
        t1[c * HW + p] = f2bfu(a1[c] * inv);
        t2[c * HW + p] = f2bfu(a2[c] * inv);
    }
}

// fused separable blur (LDS) + bilateral (t2 LDS-staged) + update.
// 128x16 tile, 8 px/thread; wtab read as uint4 (8 weights); XCD-swizzled.
// Last iteration writes out (H,W,C) directly and skips q.
__global__ __launch_bounds__(256)
void k_VF(const u16* __restrict__ t1, const u16* __restrict__ t2,
          const u16* __restrict__ wtab, const float* __restrict__ msum,
          const float* __restrict__ inv_sp, const float* __restrict__ inv_bn,
          const float* __restrict__ unp,
          const float* __restrict__ loww, const float* __restrict__ highw,
          float* __restrict__ q, float* __restrict__ outp) {
    GKDEF;
    __shared__ float A[28 * 144];   // t1 halo (28 rows); reused for t2 (20 rows)
    __shared__ float B[16 * 144];   // blurV output
    // decode: 1512 = 8 xcd * 189; 189 = 21 c * 9; 9 = 3 xt * 3 ytl
    int bid = blockIdx.x;
    int xcd = bid & 7;
    int idx = bid >> 3;                    // 0..188
    int c   = idx % 21;
    int rem = idx / 21;                    // 0..8
    int xt  = rem % 3;
    int ytl = rem / 3;                     // 0..2
    int gyt = xcd * 3 + ytl;               // 0..23
    int x0 = xt * 128;
    int y0 = gyt * 16;
    const u16* t1p = t1 + (size_t)c * HW;

    // ---- stage A = t1 halo rows y0-6..y0+21 (zero-padded), bf16 -> fp32 ----
    for (int i = threadIdx.x; i < 28 * 36; i += 256) {
        int r = i / 36, q4 = i - r * 36;
        int gy = y0 - 6 + r;
        int gx = x0 - 8 + q4 * 4;
        float4 v;
        if (gy < 0 || gy >= H) {
            v.x = v.y = v.z = v.w = 0.f;
        } else if (gx >= 0 && gx + 3 < W) {
            ushort4 u = *(const ushort4*)(t1p + gy * W + gx);
            v.x = bfu2f(u.x); v.y = bfu2f(u.y); v.z = bfu2f(u.z); v.w = bfu2f(u.w);
        } else {
            float e[4];
            for (int j = 0; j < 4; j++) {
                int xx = gx + j;
                e[j] = (xx >= 0 && xx < W) ? bfu2f(t1p[gy * W + xx]) : 0.f;
            }
            v.x = e[0]; v.y = e[1]; v.z = e[2]; v.w = e[3];
        }
        *(float4*)(A + r * 144 + q4 * 4) = v;
    }
    __syncthreads();

    // ---- blurV: B[r][col] = sum_d gk[d] * A[r+d][col], r=0..15 ----
    for (int i = threadIdx.x; i < 16 * 144; i += 256) {
        int r = i / 144, col = i - r * 144;
        float a = 0.f;
        for (int d = 0; d < 13; d++) a += gk[d] * A[(r + d) * 144 + col];
        B[i] = a;
    }
    __syncthreads();

    int row = threadIdx.x >> 4;            // 0..15
    int xq  = (threadIdx.x & 15) * 8;      // 0..120
    int y   = y0 + row;
    int x8  = x0 + xq;
    int p8  = y * W + x8;

    // horizontal 13-tap from LDS B: window of 20
    float bw[20];
    for (int i = 0; i < 20; i++) bw[i] = B[row * 144 + xq + 2 + i];
    float sp_[8];
    for (int j = 0; j < 8; j++) {
        float a = 0.f;
        for (int t = 0; t < 13; t++) a += gk[t] * bw[j + t];
        sp_[j] = a;
    }

    // ---- stage t2 tile into A (rows y0-2..y0+17, cols x0-8..x0+135) ----
    const u16* t2p = t2 + (size_t)c * HW;
    for (int i = threadIdx.x; i < 20 * 36; i += 256) {
        int r = i / 36, q4 = i - r * 36;
        int gy = min(max(y0 - 2 + r, 0), H - 1);        // clamped; OOB weight 0
        int gx = min(max(x0 - 8 + q4 * 4, 0), W - 4);   // clamped; OOB weight 0
        ushort4 u = *(const ushort4*)(t2p + gy * W + gx);
        float4 v;
        v.x = bfu2f(u.x); v.y = bfu2f(u.y); v.z = bfu2f(u.z); v.w = bfu2f(u.w);
        *(float4*)(A + r * 144 + q4 * 4) = v;
    }
    __syncthreads();

    // ---- bilateral from LDS; weights via uint4 = 8 bf16 each ----
    float bi[8] = {0.f, 0.f, 0.f, 0.f, 0.f, 0.f, 0.f, 0.f};
    int lb = xq + 8;                        // local col of x8 in the 144-tile
    int t = 0;
    for (int dy = -2; dy <= 2; dy++) {
        int r = row - dy + 2;               // 0..19
        float rr[16];
        float4 v0 = *(const float4*)(A + r * 144 + lb - 4);
        float4 v1 = *(const float4*)(A + r * 144 + lb);
        float4 v2 = *(const float4*)(A + r * 144 + lb + 4);
        float4 v3 = *(const float4*)(A + r * 144 + lb + 8);
        rr[0]  = v0.x; rr[1]  = v0.y; rr[2]  = v0.z; rr[3]  = v0.w;
        rr[4]  = v1.x; rr[5]  = v1.y; rr[6]  = v1.z; rr[7]  = v1.w;
        rr[8]  = v2.x; rr[9]  = v2.y; rr[10] = v2.z; rr[11] = v2.w;
        rr[12] = v3.x; rr[13] = v3.y; rr[14] = v3.z; rr[15] = v3.w;
        for (int dx = -2; dx <= 2; dx++, t++) {
            uint4 wu = *(const uint4*)(wtab + (size_t)t * HW + p8);
            float w0 = bflo(wu.x), w1 = bfhi(wu.x);
            float w2 = bflo(wu.y), w3 = bfhi(wu.y);
            float w4 = bflo(wu.z), w5 = bfhi(wu.z);
            float w6 = bflo(wu.w), w7 = bfhi(wu.w);
            int o = 4 - dx;
            bi[0] += w0 * rr[0 + o]; bi[1] += w1 * rr[1 + o];
            bi[2] += w2 * rr[2 + o]; bi[3] += w3 * rr[3 + o];
            bi[4] += w4 * rr[4 + o]; bi[5] += w5 * rr[5 + o];
            bi[6] += w6 * rr[6 + o]; bi[7] += w7 * rr[7 + o];
        }
    }

    // ---- update: q/out = un - pairwise + superpixel closed form (8 px) ----
    float lc = loww[c], hw_ = highw[0];
    float msa[8], isa[8], iba[8], qoa[8], una[8];
    {
        float4 a, b;
        a = *(const float4*)(msum + p8); b = *(const float4*)(msum + p8 + 4);
        msa[0]=a.x; msa[1]=a.y; msa[2]=a.z; msa[3]=a.w;
        msa[4]=b.x; msa[5]=b.y; msa[6]=b.z; msa[7]=b.w;
        a = *(const float4*)(inv_sp + p8); b = *(const float4*)(inv_sp + p8 + 4);
        isa[0]=a.x; isa[1]=a.y; isa[2]=a.z; isa[3]=a.w;
        isa[4]=b.x; isa[5]=b.y; isa[6]=b.z; isa[7]=b.w;
        a = *(const float4*)(inv_bn + p8); b = *(const float4*)(inv_bn + p8 + 4);
        iba[0]=a.x; iba[1]=a.y; iba[2]=a.z; iba[3]=a.w;
        iba[4]=b.x; iba[5]=b.y; iba[6]=b.z; iba[7]=b.w;
        a = *(const float4*)(unp + (size_t)c * HW + p8);
        b = *(const float4*)(unp + (size_t)c * HW + p8 + 4);
        una[0]=a.x; una[1]=a.y; una[2]=a.z; una[3]=a.w;
        una[4]=b.x; una[5]=b.y; una[6]=b.z; una[7]=b.w;
        a = *(const float4*)(q + (size_t)c * HW + p8);
        b = *(const float4*)(q + (size_t)c * HW + p8 + 4);
        qoa[0]=a.x; qoa[1]=a.y; qoa[2]=a.z; qoa[3]=a.w;
        qoa[4]=b.x; qoa[5]=b.y; qoa[6]=b.z; qoa[7]=b.w;
    }
    float outv[8];
    for (int j = 0; j < 8; j++) {
        float pw = sp_[j] * isa[j] + bi[j] * iba[j];
        float qo = qoa[j];
        float ft = (msa[j] * qo + (NCLIQ - msa[j])) / qo;
        float su = lc * ft + hw_ * (1.0f - ft);
        outv[j] = una[j] - pw + su;
    }
    if (outp) {   // last iteration: final (H,W,C) layout directly
        for (int j = 0; j < 8; j++) outp[(size_t)(p8 + j) * C + c] = outv[j];
    } else {
        float4 r0, r1;
        r0.x = outv[0]; r0.y = outv[1]; r0.z = outv[2]; r0.w = outv[3];
        r1.x = outv[4]; r1.y = outv[5]; r1.z = outv[6]; r1.w = outv[7];
        float* qp = q + (size_t)c * HW + p8;
        *(float4*)qp = r0;
        *(float4*)(qp + 4) = r1;
    }
}

// ---- launch -----------------------------------------------------------------

extern "C" void kernel_launch(void* const* d_in, const int* in_sizes, int n_in,
                              void* d_out, int out_size, void* d_ws, size_t ws_size,
                              hipStream_t stream) {
    const float* un    = (const float*)d_in[0];
    const float* rgb   = (const float*)d_in[1];
    const int*   sp    = (const int*)d_in[2];
    const float* Wsp   = (const float*)d_in[3];
    const float* Wbi   = (const float*)d_in[4];
    const float* Cm    = (const float*)d_in[5];
    const float* loww  = (const float*)d_in[6];
    const float* highw = (const float*)d_in[7];
    float* out = (float*)d_out;

    // ws layout ~46.5 MB
    float* ws    = (float*)d_ws;
    float* q     = ws;                            // C*HW fp32
    float* unp   = q   + (size_t)C * HW;          // C*HW fp32
    float* msum  = unp + (size_t)C * HW;          // HW
    float* isp   = msum + HW;                     // HW
    float* ibn   = isp + HW;                      // HW
    float* M1    = ibn + HW;                      // C*C
    float* M2    = M1 + C * C;                    // C*C
    u16*   t1    = (u16*)(M2 + C * C + 6);        // C*HW bf16 (16B-aligned)
    u16*   t2    = t1 + (size_t)C * HW;           // C*HW bf16
    u16*   wtab  = t2 + (size_t)C * HW;           // 25*HW bf16

    dim3 blk(256);
    dim3 gpix(HW / 256);                 // 576
    dim3 gVF(8 * 189);                   // 1512: 128x16 tiles x 21 ch, swizzled

    // prep includes iteration 0's ST
    k_prep<<<gpix, blk, 0, stream>>>(un, rgb, sp, Wsp, Wbi, Cm,
                                     q, unp, wtab, msum, isp, ibn, M1, M2,
                                     t1, t2);
    for (int it = 0; it < 5; it++) {
        k_VF<<<gVF, blk, 0, stream>>>(t1, t2, wtab, msum, isp, ibn,
                                      unp, loww, highw, q,
                                      (it == 4) ? out : (float*)nullptr);
        if (it < 4)
            k_ST<<<gpix, blk, 0, stream>>>(q, M1, M2, t1, t2);
    }
}